// Round 14
// baseline (155.784 us; speedup 1.0000x reference)
//
#include <hip/hip_runtime.h>

#define BN 262144
#define HALF (BN / 2)
#define LNUM 15
// slab: 151 stages x 72 floats, per stage: [bias 8][W 64 row-major]; stage 150 = dup of 0
#define NSTG 151
#define NF4 (NSTG * 18)
#define LOG2E 1.4426950408889634f
#define LN2 0.6931471805599453f
#define L2CLIP 7.2134752044448170f   // 5*log2e

extern "C" __global__ void build_slab(
    const float* __restrict__ Wi, const float* __restrict__ bi,
    const float* __restrict__ Wh, const float* __restrict__ bh,
    const float* __restrict__ Wo, const float* __restrict__ bo,
    float* __restrict__ slab) {
    int idx = blockIdx.x * 256 + threadIdx.x;
    if (idx >= NSTG * 72) return;
    int sl = idx / 72, k = idx % 72;
    if (sl == NSTG - 1) sl = 0;
    const int l = sl / 10, r = sl % 10, net = r / 5, st = r % 5;
    const int nb = l * 2 + net;
    // net0 stage4 produces log_s: pre-scale by log2e so kernel uses exp2
    const float sc = (net == 0 && st == 4) ? LOG2E : 1.0f;
    float v;
    if (k < 8) {
        if (st == 0)      v = bi[nb * 8 + k];
        else if (st < 4)  v = bh[(nb * 3 + (st - 1)) * 8 + k];
        else              v = bo[nb * 8 + k] * sc;
    } else {
        const int kk = k - 8;
        if (st == 0)      v = Wi[nb * 64 + kk];
        else if (st < 4)  v = Wh[(nb * 3 + (st - 1)) * 64 + kk];
        else              v = Wo[nb * 64 + kk] * sc;
    }
    slab[idx] = v;
}

// cumulative maps: logical x[j] at layer l lives at physical slot c[l][j]
extern "C" __global__ void compose_perms(const int* __restrict__ perms, int* __restrict__ c) {
    if (threadIdx.x != 0 || blockIdx.x != 0) return;
    int cur[16];
    for (int j = 0; j < 16; ++j) { cur[j] = j; c[j] = j; }
    for (int l = 0; l < LNUM; ++l) {
        int nx[16];
        for (int j = 0; j < 16; ++j) nx[j] = cur[perms[l * 16 + j]];
        for (int j = 0; j < 16; ++j) { c[(l + 1) * 16 + j] = nx[j]; cur[j] = nx[j]; }
    }
}

// broadcast weight j from lane-resident VGPR via readlane (compile-time lane)
#define RL(v, j) __uint_as_float(__builtin_amdgcn_readlane(__float_as_uint(v), (j)))

// one 8x8 stage: weights broadcast from VC0 (bias@0..7, rows0..6@8..63) and
// VC1 (row7 @ lanes 0..7); first issue the 2 ds_read_b32 prefetching the
// NEXT stage's lane values (overlaps the ~430-cyc FMA block).
#define STG(IN, OUT, DOLR, VC0, VC1, VN0, VN1, NXTOFF)                         \
    {                                                                          \
        VN0 = w0p[NXTOFF];                                                     \
        VN1 = w1p[NXTOFF];                                                     \
        _Pragma("unroll") for (int o = 0; o < 8; ++o) {                        \
            const float bb = RL(VC0, o);                                       \
            OUT[0][o] = bb; OUT[1][o] = bb;                                    \
        }                                                                      \
        _Pragma("unroll") for (int ii = 0; ii < 7; ++ii)                       \
            _Pragma("unroll") for (int o = 0; o < 8; ++o) {                    \
                const float w = RL(VC0, 8 + ii * 8 + o);                       \
                OUT[0][o] = fmaf(IN[0][ii], w, OUT[0][o]);                     \
                OUT[1][o] = fmaf(IN[1][ii], w, OUT[1][o]);                     \
            }                                                                  \
        _Pragma("unroll") for (int o = 0; o < 8; ++o) {                        \
            const float w = RL(VC1, o);                                        \
            const float a0 = fmaf(IN[0][7], w, OUT[0][o]);                     \
            const float a1 = fmaf(IN[1][7], w, OUT[1][o]);                     \
            OUT[0][o] = (DOLR) ? fmaxf(a0, 0.01f * a0) : a0;                   \
            OUT[1][o] = (DOLR) ? fmaxf(a1, 0.01f * a1) : a1;                   \
        }                                                                      \
    }

// S=2 samples/thread, 8 waves/CU. x LDS-resident (composed perms index it);
// weights: 2 per-lane ds_read_b32 per stage + v_readlane broadcast -> LDS
// return-BW (r13's wall: 180 b128/wave/layer) drops ~99%.
extern "C" __global__ void __launch_bounds__(512) flow_fwd(
    const float* __restrict__ z, const float* __restrict__ slab,
    const int* __restrict__ cperm,
    float* __restrict__ outy, float* __restrict__ outld) {
    __shared__ float wls[NSTG * 72];  // 43.5 KB
    __shared__ float xs[512 * 33];    // 67.6 KB: per-thread {A:0..15, B:16..31, pad}
    const int t = threadIdx.x;
    const int lane = t & 63;
    const long i = (long)blockIdx.x * 512 + t;
    float* __restrict__ myx = &xs[t * 33];

    {   // one-time block-cooperative slab copy
        float4* wd = reinterpret_cast<float4*>(wls);
        const float4* gs = reinterpret_cast<const float4*>(slab);
        for (int k = t; k < NF4; k += 512) wd[k] = gs[k];
    }
    {   // load z into the LDS-resident x slots
        const float4* zp = reinterpret_cast<const float4*>(z + i * 16);
        const float4* zq = reinterpret_cast<const float4*>(z + (i + HALF) * 16);
#pragma unroll
        for (int q = 0; q < 4; ++q) {
            float4 a = zp[q], b = zq[q];
            myx[4 * q] = a.x; myx[4 * q + 1] = a.y; myx[4 * q + 2] = a.z; myx[4 * q + 3] = a.w;
            myx[16 + 4 * q] = b.x; myx[17 + 4 * q] = b.y; myx[18 + 4 * q] = b.z; myx[19 + 4 * q] = b.w;
        }
    }
    float ld2A = 0.f, ld2B = 0.f;
    __syncthreads();

    // lane-resident stage values, ping-pong A/B
    float vA0 = wls[lane], vA1 = wls[64 + (lane & 7)];
    float vB0, vB1;

#pragma unroll 1
    for (int l = 0; l < LNUM; ++l) {
        const int* __restrict__ cl = cperm + l * 16;        // block-uniform -> s_load
        const float* __restrict__ w0p = wls + l * 720 + lane;
        const float* __restrict__ w1p = wls + l * 720 + 64 + (lane & 7);
        float in2[2][8];
#pragma unroll
        for (int j = 0; j < 8; ++j) {   // gather z_l once, reused by both nets
            const int off = cl[j];
            in2[0][j] = myx[off];
            in2[1][j] = myx[16 + off];
        }
        float h[2][8], g[2][8], sf[2][8], bf[2][8];
        // net 0: log_s (log2 domain); stages l*10 .. l*10+4
        STG(in2, h, 1, vA0, vA1, vB0, vB1, 1 * 72)
        STG(h, g, 1,   vB0, vB1, vA0, vA1, 2 * 72)
        STG(g, h, 1,   vA0, vA1, vB0, vB1, 3 * 72)
        STG(h, g, 1,   vB0, vB1, vA0, vA1, 4 * 72)
        STG(g, sf, 0,  vA0, vA1, vB0, vB1, 5 * 72)
        // net 1: b; stages l*10+5 .. l*10+9
        STG(in2, h, 1, vB0, vB1, vA0, vA1, 6 * 72)
        STG(h, g, 1,   vA0, vA1, vB0, vB1, 7 * 72)
        STG(g, h, 1,   vB0, vB1, vA0, vA1, 8 * 72)
        STG(h, g, 1,   vA0, vA1, vB0, vB1, 9 * 72)
        STG(g, bf, 0,  vB0, vB1, vA0, vA1, 10 * 72)   // prefetch = next layer stage 0 (dup at l=14)

#pragma unroll
        for (int k = 0; k < 8; ++k) {
            const int off = cl[8 + k];
            const float cA = fminf(fmaxf(sf[0][k], -L2CLIP), L2CLIP);
            const float cB = fminf(fmaxf(sf[1][k], -L2CLIP), L2CLIP);
            ld2A += cA; ld2B += cB;
            myx[off]      = fmaf(__builtin_amdgcn_exp2f(cA) + 1e-6f, myx[off],      bf[0][k]);
            myx[16 + off] = fmaf(__builtin_amdgcn_exp2f(cB) + 1e-6f, myx[16 + off], bf[1][k]);
        }
    }

    {   // final gather through c[15] and store
        const int* __restrict__ cf = cperm + LNUM * 16;
        float4 oa[4], ob[4];
#pragma unroll
        for (int q = 0; q < 4; ++q) {
            const int c0 = cf[4 * q], c1 = cf[4 * q + 1], c2 = cf[4 * q + 2], c3 = cf[4 * q + 3];
            oa[q].x = myx[c0]; oa[q].y = myx[c1]; oa[q].z = myx[c2]; oa[q].w = myx[c3];
            ob[q].x = myx[16 + c0]; ob[q].y = myx[16 + c1];
            ob[q].z = myx[16 + c2]; ob[q].w = myx[16 + c3];
        }
        float4* ya = reinterpret_cast<float4*>(outy + i * 16);
        float4* yb = reinterpret_cast<float4*>(outy + (i + HALF) * 16);
#pragma unroll
        for (int q = 0; q < 4; ++q) { ya[q] = oa[q]; yb[q] = ob[q]; }
        outld[i] = ld2A * LN2;
        outld[i + HALF] = ld2B * LN2;
    }
}

extern "C" void kernel_launch(void* const* d_in, const int* in_sizes, int n_in,
                              void* d_out, int out_size, void* d_ws, size_t ws_size,
                              hipStream_t stream) {
    const float* z = (const float*)d_in[0];
    const float* Wi = (const float*)d_in[1];
    const float* bi = (const float*)d_in[2];
    const float* Wh = (const float*)d_in[3];
    const float* bh = (const float*)d_in[4];
    const float* Wo = (const float*)d_in[5];
    const float* bo = (const float*)d_in[6];
    const int* perms = (const int*)d_in[7];
    float* out = (float*)d_out;
    float* slab = (float*)d_ws;                    // NSTG*72 floats
    int* cperm = (int*)(slab + NSTG * 72);         // (LNUM+1)*16 ints

    hipLaunchKernelGGL(build_slab, dim3((NSTG * 72 + 255) / 256), dim3(256), 0, stream,
                       Wi, bi, Wh, bh, Wo, bo, slab);
    hipLaunchKernelGGL(compose_perms, dim3(1), dim3(64), 0, stream, perms, cperm);
    hipLaunchKernelGGL(flow_fwd, dim3(HALF / 512), dim3(512), 0, stream,
                       z, slab, cperm, out, out + (size_t)BN * 16);
}

// Round 15
// 138.430 us; speedup vs baseline: 1.1254x; 1.1254x over previous
//
#include <hip/hip_runtime.h>

#define BN 262144
#define S4 4
#define QS (BN / S4)
#define LNUM 15
// slab: 151 stages x 72 floats, per stage: [bias 8][W 64 row-major]; stage 150 = dup of 0
#define NSTG 151
#define NF4 (NSTG * 18)
#define LOG2E 1.4426950408889634f
#define LN2 0.6931471805599453f
#define L2CLIP 7.2134752044448170f   // 5*log2e

typedef __attribute__((ext_vector_type(4))) float f4;

extern "C" __global__ void build_slab(
    const float* __restrict__ Wi, const float* __restrict__ bi,
    const float* __restrict__ Wh, const float* __restrict__ bh,
    const float* __restrict__ Wo, const float* __restrict__ bo,
    float* __restrict__ slab) {
    int idx = blockIdx.x * 256 + threadIdx.x;
    if (idx >= NSTG * 72) return;
    int sl = idx / 72, k = idx % 72;
    if (sl == NSTG - 1) sl = 0;
    const int l = sl / 10, r = sl % 10, net = r / 5, st = r % 5;
    const int nb = l * 2 + net;
    const float sc = (net == 0 && st == 4) ? LOG2E : 1.0f;   // log2-domain fold
    float v;
    if (k < 8) {
        if (st == 0)      v = bi[nb * 8 + k];
        else if (st < 4)  v = bh[(nb * 3 + (st - 1)) * 8 + k];
        else              v = bo[nb * 8 + k] * sc;
    } else {
        const int kk = k - 8;
        if (st == 0)      v = Wi[nb * 64 + kk];
        else if (st < 4)  v = Wh[(nb * 3 + (st - 1)) * 64 + kk];
        else              v = Wo[nb * 64 + kk] * sc;
    }
    slab[idx] = v;
}

extern "C" __global__ void compose_perms(const int* __restrict__ perms, int* __restrict__ c) {
    if (threadIdx.x != 0 || blockIdx.x != 0) return;
    int cur[16];
    for (int j = 0; j < 16; ++j) { cur[j] = j; c[j] = j; }
    for (int l = 0; l < LNUM; ++l) {
        int nx[16];
        for (int j = 0; j < 16; ++j) nx[j] = cur[perms[l * 16 + j]];
        for (int j = 0; j < 16; ++j) { c[(l + 1) * 16 + j] = nx[j]; cur[j] = nx[j]; }
    }
}

// float k of an 18-f4 stage buffer (compile-time k)
#define GBX(W, k) (W[(k) / 4][(k) % 4])

// pin all 18 loaded f4s: values become asm outputs -> cannot be remat'd from
// LDS; compiler must hold them in VGPRs from here to use (rule #17 applied
// as a forcing mechanism). sched_barrier stops load sinking / compute hoist.
#define PINW(W) asm volatile("" : "+v"(W[0]),"+v"(W[1]),"+v"(W[2]),"+v"(W[3]), \
    "+v"(W[4]),"+v"(W[5]),"+v"(W[6]),"+v"(W[7]),"+v"(W[8]),"+v"(W[9]),        \
    "+v"(W[10]),"+v"(W[11]),"+v"(W[12]),"+v"(W[13]),"+v"(W[14]),"+v"(W[15]),  \
    "+v"(W[16]),"+v"(W[17]))

#define PREF_PIN(W, SIDX)                                                     \
    {                                                                         \
        const f4* sp = &wls[(SIDX) * 18];                                     \
        _Pragma("unroll") for (int j = 0; j < 18; ++j) W[j] = sp[j];          \
        PINW(W);                                                              \
        __builtin_amdgcn_sched_barrier(0);                                    \
    }

// quad-sample 8x8 matvec from pinned stage buffer; bias folded into row 0
#define MV(IN, OUT, W, LR)                                                    \
    _Pragma("unroll") for (int o = 0; o < 8; ++o) {                           \
        const float w0 = GBX(W, 8 + o), bb = GBX(W, o);                       \
        _Pragma("unroll") for (int s = 0; s < 4; ++s)                         \
            OUT[s][o] = fmaf(IN[s][0], w0, bb);                               \
    }                                                                         \
    _Pragma("unroll") for (int i2 = 1; i2 < 8; ++i2)                          \
        _Pragma("unroll") for (int o = 0; o < 8; ++o) {                       \
            const float w = GBX(W, 8 + i2 * 8 + o);                           \
            _Pragma("unroll") for (int s = 0; s < 4; ++s)                     \
                OUT[s][o] = fmaf(IN[s][i2], w, OUT[s][o]);                    \
        }                                                                     \
    if (LR) {                                                                 \
        _Pragma("unroll") for (int s = 0; s < 4; ++s)                         \
            _Pragma("unroll") for (int o = 0; o < 8; ++o)                     \
                OUT[s][o] = fmaxf(OUT[s][o], 0.01f * OUT[s][o]);              \
    }

// prefetch stage PIDX into PB, compute current stage from CB
#define STGM(IN, OUT, LR, PB, PIDX, CB) PREF_PIN(PB, PIDX) MV(IN, OUT, CB, LR)

// S=4 samples/thread, 256 thr, 1 block/CU (4 waves): weight LDS traffic
// halves vs r13 (the measured wall). Pinned ping-pong prefetch keeps the
// stage buffer genuinely in VGPRs at 1 wave/SIMD.
extern "C" __global__ void __launch_bounds__(256, 1) flow_fwd(
    const float* __restrict__ z, const float* __restrict__ slab,
    const int* __restrict__ cperm,
    float* __restrict__ outy, float* __restrict__ outld) {
    __shared__ f4 wls[NF4];           // 43.5 KB
    __shared__ float xs[256 * 65];    // 66.6 KB: per-thread 4x16 x-slots + pad (65 odd)
    const int t = threadIdx.x;
    const int i0 = blockIdx.x * 256 + t;
    float* __restrict__ myx = &xs[t * 65];

    {   // one-time block-cooperative slab copy
        const f4* gs = reinterpret_cast<const f4*>(slab);
        for (int k = t; k < NF4; k += 256) wls[k] = gs[k];
    }
#pragma unroll
    for (int s = 0; s < 4; ++s) {   // z -> LDS-resident x slots
        const float4* zp = reinterpret_cast<const float4*>(z + (long)(i0 + s * QS) * 16);
#pragma unroll
        for (int q = 0; q < 4; ++q) {
            float4 a = zp[q];
            myx[s * 16 + 4 * q] = a.x; myx[s * 16 + 4 * q + 1] = a.y;
            myx[s * 16 + 4 * q + 2] = a.z; myx[s * 16 + 4 * q + 3] = a.w;
        }
    }
    float ld[4] = {0.f, 0.f, 0.f, 0.f};
    __syncthreads();

    f4 WA[18], WB[18];
    PREF_PIN(WA, 0)

#pragma unroll 1
    for (int l = 0; l < LNUM; ++l) {
        const int* __restrict__ cl = cperm + l * 16;   // block-uniform -> s_load
        const int base = l * 10;
        float in2[4][8];
#pragma unroll
        for (int j = 0; j < 8; ++j) {   // gather z_l once, both nets reuse
            const int off = cl[j];
#pragma unroll
            for (int s = 0; s < 4; ++s) in2[s][j] = myx[s * 16 + off];
        }
        float h[4][8], g[4][8], sf[4][8], bf[4][8];
        // net 0: log_s (log2 domain)
        STGM(in2, h, 1, WB, base + 1, WA)
        STGM(h, g, 1,   WA, base + 2, WB)
        STGM(g, h, 1,   WB, base + 3, WA)
        STGM(h, g, 1,   WA, base + 4, WB)
        STGM(g, sf, 0,  WB, base + 5, WA)
        // net 1: b
        STGM(in2, h, 1, WA, base + 6, WB)
        STGM(h, g, 1,   WB, base + 7, WA)
        STGM(g, h, 1,   WA, base + 8, WB)
        STGM(h, g, 1,   WB, base + 9, WA)
        STGM(g, bf, 0,  WA, base + 10, WB)   // prefetch = next layer stage 0 (dup @150)

#pragma unroll
        for (int k = 0; k < 8; ++k) {
            const int off = cl[8 + k];
#pragma unroll
            for (int s = 0; s < 4; ++s) {
                const float cs = fminf(fmaxf(sf[s][k], -L2CLIP), L2CLIP);
                ld[s] += cs;
                myx[s * 16 + off] = fmaf(__builtin_amdgcn_exp2f(cs) + 1e-6f,
                                         myx[s * 16 + off], bf[s][k]);
            }
        }
    }

    {   // final gather through c[15] and store
        const int* __restrict__ cf = cperm + LNUM * 16;
#pragma unroll
        for (int s = 0; s < 4; ++s) {
            float4 o[4];
#pragma unroll
            for (int q = 0; q < 4; ++q) {
                o[q].x = myx[s * 16 + cf[4 * q]];
                o[q].y = myx[s * 16 + cf[4 * q + 1]];
                o[q].z = myx[s * 16 + cf[4 * q + 2]];
                o[q].w = myx[s * 16 + cf[4 * q + 3]];
            }
            float4* ya = reinterpret_cast<float4*>(outy + (long)(i0 + s * QS) * 16);
#pragma unroll
            for (int q = 0; q < 4; ++q) ya[q] = o[q];
            outld[i0 + s * QS] = ld[s] * LN2;
        }
    }
}

extern "C" void kernel_launch(void* const* d_in, const int* in_sizes, int n_in,
                              void* d_out, int out_size, void* d_ws, size_t ws_size,
                              hipStream_t stream) {
    const float* z = (const float*)d_in[0];
    const float* Wi = (const float*)d_in[1];
    const float* bi = (const float*)d_in[2];
    const float* Wh = (const float*)d_in[3];
    const float* bh = (const float*)d_in[4];
    const float* Wo = (const float*)d_in[5];
    const float* bo = (const float*)d_in[6];
    const int* perms = (const int*)d_in[7];
    float* out = (float*)d_out;
    float* slab = (float*)d_ws;                    // NSTG*72 floats
    int* cperm = (int*)(slab + NSTG * 72);         // (LNUM+1)*16 ints

    hipLaunchKernelGGL(build_slab, dim3((NSTG * 72 + 255) / 256), dim3(256), 0, stream,
                       Wi, bi, Wh, bh, Wo, bo, slab);
    hipLaunchKernelGGL(compose_perms, dim3(1), dim3(64), 0, stream, perms, cperm);
    hipLaunchKernelGGL(flow_fwd, dim3(QS / 256), dim3(256), 0, stream,
                       z, slab, cperm, out, out + (size_t)BN * 16);
}

// Round 17
// 129.531 us; speedup vs baseline: 1.2027x; 1.0687x over previous
//
#include <hip/hip_runtime.h>

#define BN 262144
#define S4 4
#define QS (BN / S4)
#define LNUM 15
// slab: 151 stages x 72 floats, per stage: [bias 8][W 64 row-major]; stage 150 = dup of 0
#define NSTG 151
#define NF4 (NSTG * 18)
#define LOG2E 1.4426950408889634f
#define LN2 0.6931471805599453f
#define L2CLIP 7.2134752044448170f   // 5*log2e

typedef __attribute__((ext_vector_type(4))) float f4;

extern "C" __global__ void build_slab(
    const float* __restrict__ Wi, const float* __restrict__ bi,
    const float* __restrict__ Wh, const float* __restrict__ bh,
    const float* __restrict__ Wo, const float* __restrict__ bo,
    float* __restrict__ slab) {
    int idx = blockIdx.x * 256 + threadIdx.x;
    if (idx >= NSTG * 72) return;
    int sl = idx / 72, k = idx % 72;
    if (sl == NSTG - 1) sl = 0;
    const int l = sl / 10, r = sl % 10, net = r / 5, st = r % 5;
    const int nb = l * 2 + net;
    const float sc = (net == 0 && st == 4) ? LOG2E : 1.0f;   // log2-domain fold
    float v;
    if (k < 8) {
        if (st == 0)      v = bi[nb * 8 + k];
        else if (st < 4)  v = bh[(nb * 3 + (st - 1)) * 8 + k];
        else              v = bo[nb * 8 + k] * sc;
    } else {
        const int kk = k - 8;
        if (st == 0)      v = Wi[nb * 64 + kk];
        else if (st < 4)  v = Wh[(nb * 3 + (st - 1)) * 64 + kk];
        else              v = Wo[nb * 64 + kk] * sc;
    }
    slab[idx] = v;
}

extern "C" __global__ void compose_perms(const int* __restrict__ perms, int* __restrict__ c) {
    if (threadIdx.x != 0 || blockIdx.x != 0) return;
    int cur[16];
    for (int j = 0; j < 16; ++j) { cur[j] = j; c[j] = j; }
    for (int l = 0; l < LNUM; ++l) {
        int nx[16];
        for (int j = 0; j < 16; ++j) nx[j] = cur[perms[l * 16 + j]];
        for (int j = 0; j < 16; ++j) { c[(l + 1) * 16 + j] = nx[j]; cur[j] = nx[j]; }
    }
}

// float k of an 18-f4 stage buffer (compile-time k)
#define GBX(W, k) (W[(k) / 4][(k) % 4])

// volatile asm ds_read_b128: pinned at issue, un-remat'able, un-sinkable.
// NOTE: compiler does NOT model asm lgkmcnt -> we wait manually (rule #18).
#define PREF_ASM(W, STOFF)                                                    \
    { _Pragma("unroll") for (int j = 0; j < 18; ++j)                          \
        asm volatile("ds_read_b128 %0, %1 offset:%2"                          \
                     : "=v"(W[j]) : "v"(laddr), "i"((STOFF) + j * 16)); }

// quad-sample 8x8 matvec from stage buffer; bias folded into row 0
#define MV(IN, OUT, W, LR)                                                    \
    _Pragma("unroll") for (int o = 0; o < 8; ++o) {                           \
        const float w0 = GBX(W, 8 + o), bb = GBX(W, o);                       \
        _Pragma("unroll") for (int s = 0; s < 4; ++s)                         \
            OUT[s][o] = fmaf(IN[s][0], w0, bb);                               \
    }                                                                         \
    _Pragma("unroll") for (int i2 = 1; i2 < 8; ++i2)                          \
        _Pragma("unroll") for (int o = 0; o < 8; ++o) {                       \
            const float w = GBX(W, 8 + i2 * 8 + o);                           \
            _Pragma("unroll") for (int s = 0; s < 4; ++s)                     \
                OUT[s][o] = fmaf(IN[s][i2], w, OUT[s][o]);                    \
        }                                                                     \
    if (LR) {                                                                 \
        _Pragma("unroll") for (int s = 0; s < 4; ++s)                         \
            _Pragma("unroll") for (int o = 0; o < 8; ++o)                     \
                OUT[s][o] = fmaxf(OUT[s][o], 0.01f * OUT[s][o]);              \
    }

// stage: [current buf guaranteed ready] -> issue next -> compute current.
// lgkmcnt(0) fires BEFORE the next issue, so it waits exactly on the current
// stage's 18 reads (+ stray compiler x-ops) -- no over-drain of the pipeline.
#define STGA(IN, OUT, LR, PB, POFF, CB)                                       \
    {                                                                         \
        asm volatile("s_waitcnt lgkmcnt(0)" ::: "memory");                    \
        __builtin_amdgcn_sched_barrier(0);                                    \
        PREF_ASM(PB, POFF)                                                    \
        MV(IN, OUT, CB, LR)                                                   \
    }

// S=4 samples/thread, 256 thr, 1 block/CU: halves per-sample weight-LDS
// traffic vs r13 (the measured 95us wall). asm-pinned ping-pong prefetch.
extern "C" __global__ void __launch_bounds__(256, 1) flow_fwd(
    const float* __restrict__ z, const float* __restrict__ slab,
    const int* __restrict__ cperm,
    float* __restrict__ outy, float* __restrict__ outld) {
    __shared__ f4 wls[NF4];           // 43.5 KB (LDS offset 0)
    __shared__ float xs[256 * 65];    // 65 KB: per-thread 4x16 x-slots (stride 65, odd)
    const int t = threadIdx.x;
    const int i0 = blockIdx.x * 256 + t;
    float* __restrict__ myx = &xs[t * 65];
    // LDS byte offset of the slab (generic->LDS: low 32 bits = LDS offset)
    const uint32_t wbyte = (uint32_t)(uintptr_t)(&wls[0]);

    {   // one-time block-cooperative slab copy
        const f4* gs = reinterpret_cast<const f4*>(slab);
        for (int k = t; k < NF4; k += 256) wls[k] = gs[k];
    }
#pragma unroll
    for (int s = 0; s < 4; ++s) {   // z -> LDS-resident x slots
        const float4* zp = reinterpret_cast<const float4*>(z + (long)(i0 + s * QS) * 16);
#pragma unroll
        for (int q = 0; q < 4; ++q) {
            float4 a = zp[q];
            myx[s * 16 + 4 * q] = a.x; myx[s * 16 + 4 * q + 1] = a.y;
            myx[s * 16 + 4 * q + 2] = a.z; myx[s * 16 + 4 * q + 3] = a.w;
        }
    }
    float ld[4] = {0.f, 0.f, 0.f, 0.f};
    __syncthreads();

    f4 WA[18], WB[18];
    {
        const uint32_t laddr = wbyte;
        PREF_ASM(WA, 0)
    }

#pragma unroll 1
    for (int l = 0; l < LNUM; ++l) {
        const int* __restrict__ cl = cperm + l * 16;        // block-uniform -> s_load
        const uint32_t laddr = wbyte + (uint32_t)l * 2880u; // layer base (720 floats)
        float in2[4][8];
#pragma unroll
        for (int j = 0; j < 8; ++j) {   // gather z_l once, both nets reuse
            const int off = cl[j];
#pragma unroll
            for (int s = 0; s < 4; ++s) in2[s][j] = myx[s * 16 + off];
        }
        float h[4][8], g[4][8], sf[4][8], bf[4][8];
        // net 0: log_s (log2 domain)
        STGA(in2, h, 1, WB, 1 * 288, WA)
        STGA(h, g, 1,   WA, 2 * 288, WB)
        STGA(g, h, 1,   WB, 3 * 288, WA)
        STGA(h, g, 1,   WA, 4 * 288, WB)
        STGA(g, sf, 0,  WB, 5 * 288, WA)
        // net 1: b
        STGA(in2, h, 1, WA, 6 * 288, WB)
        STGA(h, g, 1,   WB, 7 * 288, WA)
        STGA(g, h, 1,   WA, 8 * 288, WB)
        STGA(h, g, 1,   WB, 9 * 288, WA)
        STGA(g, bf, 0,  WA, 10 * 288, WB)   // next layer stage 0 (dup @ stage 150)

#pragma unroll
        for (int k = 0; k < 8; ++k) {
            const int off = cl[8 + k];
#pragma unroll
            for (int s = 0; s < 4; ++s) {
                const float cs = fminf(fmaxf(sf[s][k], -L2CLIP), L2CLIP);
                ld[s] += cs;
                myx[s * 16 + off] = fmaf(__builtin_amdgcn_exp2f(cs) + 1e-6f,
                                         myx[s * 16 + off], bf[s][k]);
            }
        }
    }

    {   // final gather through c[15] and store
        const int* __restrict__ cf = cperm + LNUM * 16;
#pragma unroll
        for (int s = 0; s < 4; ++s) {
            float4 o[4];
#pragma unroll
            for (int q = 0; q < 4; ++q) {
                o[q].x = myx[s * 16 + cf[4 * q]];
                o[q].y = myx[s * 16 + cf[4 * q + 1]];
                o[q].z = myx[s * 16 + cf[4 * q + 2]];
                o[q].w = myx[s * 16 + cf[4 * q + 3]];
            }
            float4* ya = reinterpret_cast<float4*>(outy + (long)(i0 + s * QS) * 16);
#pragma unroll
            for (int q = 0; q < 4; ++q) ya[q] = o[q];
            outld[i0 + s * QS] = ld[s] * LN2;
        }
    }
}

extern "C" void kernel_launch(void* const* d_in, const int* in_sizes, int n_in,
                              void* d_out, int out_size, void* d_ws, size_t ws_size,
                              hipStream_t stream) {
    const float* z = (const float*)d_in[0];
    const float* Wi = (const float*)d_in[1];
    const float* bi = (const float*)d_in[2];
    const float* Wh = (const float*)d_in[3];
    const float* bh = (const float*)d_in[4];
    const float* Wo = (const float*)d_in[5];
    const float* bo = (const float*)d_in[6];
    const int* perms = (const int*)d_in[7];
    float* out = (float*)d_out;
    float* slab = (float*)d_ws;                    // NSTG*72 floats
    int* cperm = (int*)(slab + NSTG * 72);         // (LNUM+1)*16 ints

    hipLaunchKernelGGL(build_slab, dim3((NSTG * 72 + 255) / 256), dim3(256), 0, stream,
                       Wi, bi, Wh, bh, Wo, bo, slab);
    hipLaunchKernelGGL(compose_perms, dim3(1), dim3(64), 0, stream, perms, cperm);
    hipLaunchKernelGGL(flow_fwd, dim3(QS / 256), dim3(256), 0, stream,
                       z, slab, cperm, out, out + (size_t)BN * 16);
}

// Round 19
// 102.672 us; speedup vs baseline: 1.5173x; 1.2616x over previous
//
#include <hip/hip_runtime.h>

#define BN 262144
#define HALF (BN / 2)
#define LNUM 15
// slab A (LDS, net0): 76 stages x 72 floats ([bias 8][W 64 row-major]); stage 75 = pad
// slab B (SMEM, net1): 75 stages x 72 floats, same per-stage layout
#define NSTG0 76
#define NF4 (NSTG0 * 18)
#define NTOT ((NSTG0 + 75) * 72)
#define LOG2E 1.4426950408889634f
#define LN2 0.6931471805599453f
#define L2CLIP 7.2134752044448170f   // 5*log2e

typedef __attribute__((ext_vector_type(4))) float f4;

extern "C" __global__ void build_slab(
    const float* __restrict__ Wi, const float* __restrict__ bi,
    const float* __restrict__ Wh, const float* __restrict__ bh,
    const float* __restrict__ Wo, const float* __restrict__ bo,
    float* __restrict__ slab) {
    int idx = blockIdx.x * 256 + threadIdx.x;
    if (idx >= NTOT) return;
    int sl, k, net;
    if (idx < NSTG0 * 72) {            // region A: net0 stages (LDS slab)
        sl = idx / 72; k = idx % 72; net = 0;
        if (sl == NSTG0 - 1) sl = 0;   // pad stage (prefetch overrun, never consumed)
    } else {                           // region B: net1 stages (SMEM slab)
        const int j = idx - NSTG0 * 72;
        sl = j / 72; k = j % 72; net = 1;
    }
    const int l = sl / 5, st = sl % 5;
    const int nb = l * 2 + net;
    const float sc = (net == 0 && st == 4) ? LOG2E : 1.0f;   // log2-domain fold
    float v;
    if (k < 8) {
        if (st == 0)      v = bi[nb * 8 + k];
        else if (st < 4)  v = bh[(nb * 3 + (st - 1)) * 8 + k];
        else              v = bo[nb * 8 + k] * sc;
    } else {
        const int kk = k - 8;
        if (st == 0)      v = Wi[nb * 64 + kk];
        else if (st < 4)  v = Wh[(nb * 3 + (st - 1)) * 64 + kk];
        else              v = Wo[nb * 64 + kk] * sc;
    }
    slab[idx] = v;
}

extern "C" __global__ void compose_perms(const int* __restrict__ perms, int* __restrict__ c) {
    if (threadIdx.x != 0 || blockIdx.x != 0) return;
    int cur[16];
    for (int j = 0; j < 16; ++j) { cur[j] = j; c[j] = j; }
    for (int l = 0; l < LNUM; ++l) {
        int nx[16];
        for (int j = 0; j < 16; ++j) nx[j] = cur[perms[l * 16 + j]];
        for (int j = 0; j < 16; ++j) { c[(l + 1) * 16 + j] = nx[j]; cur[j] = nx[j]; }
    }
}

// float k of a 6-f4 chunk buffer (compile-time k)
#define GB(gb, k) (gb[(k) / 4][(k) % 4])

// --- net0: LDS chunk rotation (r13 structure, 95us-validated) ---
#define CHA(IN, OUT, BUF)                                                     \
    {                                                                         \
        _Pragma("unroll") for (int o = 0; o < 8; ++o) {                       \
            const float bb = GB(BUF, o);                                      \
            const float w0 = GB(BUF, 8 + o), w1 = GB(BUF, 16 + o);            \
            _Pragma("unroll") for (int s = 0; s < 2; ++s)                     \
                OUT[s][o] = fmaf(IN[s][1], w1, fmaf(IN[s][0], w0, bb));       \
        }                                                                     \
        _Pragma("unroll") for (int j = 0; j < 6; ++j) BUF[j] = gptr[j];       \
        gptr += 6;                                                            \
        __builtin_amdgcn_sched_barrier(0);                                    \
    }
#define CHB(IN, OUT, BUF)                                                     \
    {                                                                         \
        _Pragma("unroll") for (int o = 0; o < 8; ++o) {                       \
            const float w2 = GB(BUF, o), w3 = GB(BUF, 8 + o), w4 = GB(BUF, 16 + o); \
            _Pragma("unroll") for (int s = 0; s < 2; ++s)                     \
                OUT[s][o] = fmaf(IN[s][4], w4,                                 \
                             fmaf(IN[s][3], w3, fmaf(IN[s][2], w2, OUT[s][o]))); \
        }                                                                     \
        _Pragma("unroll") for (int j = 0; j < 6; ++j) BUF[j] = gptr[j];       \
        gptr += 6;                                                            \
        __builtin_amdgcn_sched_barrier(0);                                    \
    }
#define CHC(IN, OUT, BUF, DOLR)                                               \
    {                                                                         \
        _Pragma("unroll") for (int o = 0; o < 8; ++o) {                       \
            const float w5 = GB(BUF, o), w6 = GB(BUF, 8 + o), w7 = GB(BUF, 16 + o); \
            _Pragma("unroll") for (int s = 0; s < 2; ++s) {                   \
                float a = fmaf(IN[s][7], w7,                                   \
                            fmaf(IN[s][6], w6, fmaf(IN[s][5], w5, OUT[s][o]))); \
                OUT[s][o] = (DOLR) ? fmaxf(a, 0.01f * a) : a;                 \
            }                                                                 \
        }                                                                     \
        _Pragma("unroll") for (int j = 0; j < 6; ++j) BUF[j] = gptr[j];       \
        gptr += 6;                                                            \
        __builtin_amdgcn_sched_barrier(0);                                    \
    }
#define STG(IN, OUT, DOLR) CHA(IN, OUT, B0) CHB(IN, OUT, B1) CHC(IN, OUT, B2, DOLR)

// --- net1: SMEM weights (block-uniform global indices -> s_load, r2-style) ---
#define MVS(IN, OUT, W, DOLR)                                                 \
    {                                                                         \
        _Pragma("unroll") for (int o = 0; o < 8; ++o) {                       \
            const float bb = (W)[o];                                          \
            OUT[0][o] = bb; OUT[1][o] = bb;                                   \
        }                                                                     \
        _Pragma("unroll") for (int i2 = 0; i2 < 8; ++i2)                      \
            _Pragma("unroll") for (int o = 0; o < 8; ++o) {                   \
                const float w = (W)[8 + i2 * 8 + o];                          \
                OUT[0][o] = fmaf(IN[0][i2], w, OUT[0][o]);                    \
                OUT[1][o] = fmaf(IN[1][i2], w, OUT[1][o]);                    \
            }                                                                 \
        if (DOLR) {                                                           \
            _Pragma("unroll") for (int s = 0; s < 2; ++s)                     \
                _Pragma("unroll") for (int o = 0; o < 8; ++o)                 \
                    OUT[s][o] = fmaxf(OUT[s][o], 0.01f * OUT[s][o]);          \
        }                                                                     \
    }

// S=2, 512 thr, 8 waves/CU. Weight stream split across pipes: net0 via LDS
// chunk rotation (90 b128/layer/wave, was 180), net1 via SMEM s_load
// (scalar pipe, idle until now). LDS-resident x, composed perms, exp2 fold.
extern "C" __global__ void __launch_bounds__(512) flow_fwd(
    const float* __restrict__ z, const float* __restrict__ slab,
    const int* __restrict__ cperm,
    float* __restrict__ outy, float* __restrict__ outld) {
    __shared__ f4 wls[NF4];           // 21.9 KB net0 slab
    __shared__ float xs[512 * 33];    // 67.6 KB per-thread {A:0..15, B:16..31, pad}
    const int t = threadIdx.x;
    const long i = (long)blockIdx.x * 512 + t;
    float* __restrict__ myx = &xs[t * 33];
    const float* __restrict__ gw1 = slab + NSTG0 * 72;   // net1 SMEM slab base

    {   // one-time block-cooperative net0-slab copy
        const f4* gs = reinterpret_cast<const f4*>(slab);
        for (int k = t; k < NF4; k += 512) wls[k] = gs[k];
    }
    {   // load z into the LDS-resident x slots
        const float4* zp = reinterpret_cast<const float4*>(z + i * 16);
        const float4* zq = reinterpret_cast<const float4*>(z + (i + HALF) * 16);
#pragma unroll
        for (int q = 0; q < 4; ++q) {
            float4 a = zp[q], b = zq[q];
            myx[4 * q] = a.x; myx[4 * q + 1] = a.y; myx[4 * q + 2] = a.z; myx[4 * q + 3] = a.w;
            myx[16 + 4 * q] = b.x; myx[17 + 4 * q] = b.y; myx[18 + 4 * q] = b.z; myx[19 + 4 * q] = b.w;
        }
    }
    float ld2A = 0.f, ld2B = 0.f;
    __syncthreads();

    f4 B0[6], B1[6], B2[6];
#pragma unroll
    for (int j = 0; j < 6; ++j) { B0[j] = wls[j]; B1[j] = wls[6 + j]; B2[j] = wls[12 + j]; }
    const f4* gptr = wls + 18;
    __builtin_amdgcn_sched_barrier(0);

#pragma unroll 1
    for (int l = 0; l < LNUM; ++l) {
        const int* __restrict__ cl = cperm + l * 16;       // block-uniform -> s_load
        const float* __restrict__ w1 = gw1 + l * 360;      // net1 layer base (SMEM)
        float in2[2][8];
#pragma unroll
        for (int j = 0; j < 8; ++j) {   // gather z_l once, reused by both nets
            const int off = cl[j];
            in2[0][j] = myx[off];
            in2[1][j] = myx[16 + off];
        }
        float h[2][8], g[2][8], sf[2][8], bf[2][8];
        // net 0: log_s (log2 domain) -- LDS pipe
        STG(in2, h, 1) STG(h, g, 1) STG(g, h, 1) STG(h, g, 1) STG(g, sf, 0)
        // net 1: b -- scalar pipe
        MVS(in2, h, w1 + 0, 1)
        MVS(h, g, w1 + 72, 1)
        MVS(g, h, w1 + 144, 1)
        MVS(h, g, w1 + 216, 1)
        MVS(g, bf, w1 + 288, 0)

#pragma unroll
        for (int k = 0; k < 8; ++k) {
            const int off = cl[8 + k];
            const float cA = fminf(fmaxf(sf[0][k], -L2CLIP), L2CLIP);
            const float cB = fminf(fmaxf(sf[1][k], -L2CLIP), L2CLIP);
            ld2A += cA; ld2B += cB;
            myx[off]      = fmaf(__builtin_amdgcn_exp2f(cA) + 1e-6f, myx[off],      bf[0][k]);
            myx[16 + off] = fmaf(__builtin_amdgcn_exp2f(cB) + 1e-6f, myx[16 + off], bf[1][k]);
        }
    }

    {   // final gather through c[15] and store
        const int* __restrict__ cf = cperm + LNUM * 16;
        float4 oa[4], ob[4];
#pragma unroll
        for (int q = 0; q < 4; ++q) {
            const int c0 = cf[4 * q], c1 = cf[4 * q + 1], c2 = cf[4 * q + 2], c3 = cf[4 * q + 3];
            oa[q].x = myx[c0]; oa[q].y = myx[c1]; oa[q].z = myx[c2]; oa[q].w = myx[c3];
            ob[q].x = myx[16 + c0]; ob[q].y = myx[16 + c1];
            ob[q].z = myx[16 + c2]; ob[q].w = myx[16 + c3];
        }
        float4* ya = reinterpret_cast<float4*>(outy + i * 16);
        float4* yb = reinterpret_cast<float4*>(outy + (i + HALF) * 16);
#pragma unroll
        for (int q = 0; q < 4; ++q) { ya[q] = oa[q]; yb[q] = ob[q]; }
        outld[i] = ld2A * LN2;
        outld[i + HALF] = ld2B * LN2;
    }
}

extern "C" void kernel_launch(void* const* d_in, const int* in_sizes, int n_in,
                              void* d_out, int out_size, void* d_ws, size_t ws_size,
                              hipStream_t stream) {
    const float* z = (const float*)d_in[0];
    const float* Wi = (const float*)d_in[1];
    const float* bi = (const float*)d_in[2];
    const float* Wh = (const float*)d_in[3];
    const float* bh = (const float*)d_in[4];
    const float* Wo = (const float*)d_in[5];
    const float* bo = (const float*)d_in[6];
    const int* perms = (const int*)d_in[7];
    float* out = (float*)d_out;
    float* slab = (float*)d_ws;                    // NTOT floats (A then B)
    int* cperm = (int*)(slab + NTOT);              // (LNUM+1)*16 ints

    hipLaunchKernelGGL(build_slab, dim3((NTOT + 255) / 256), dim3(256), 0, stream,
                       Wi, bi, Wh, bh, Wo, bo, slab);
    hipLaunchKernelGGL(compose_perms, dim3(1), dim3(64), 0, stream, perms, cperm);
    hipLaunchKernelGGL(flow_fwd, dim3(HALF / 512), dim3(512), 0, stream,
                       z, slab, cperm, out, out + (size_t)BN * 16);
}